// Round 4
// baseline (420.275 us; speedup 1.0000x reference)
//
#include <hip/hip_runtime.h>
#include <hip/hip_bf16.h>

// Problem constants: n=512, bsz=4, E=512, H=32 heads, d=16, scaling=0.25
//
// Decomposition:
//   force[b,i,c] = bf[c] + sum_j delta[b,i,j,c] * sum_h probs[b,h,i,j]*wv[b,h,j,c]
//   wv[b,j,h*3+c] = x[b,j,:] . Wvf[h*3+c,:] + bvf   (V GEMM folded into Wf)
//   Wvf[h*3+c,k]  = sum_d Wf[c,h*16+d]*Wv[h*16+d,k]
//
// Kernels:
//  1) wvf_prep : Wvf[128][512] (96 real rows + zero pad) + bvf[128]
//  2) gemm_xwT : out = (x @ W^T + bias)*scale, x[b,n,k]=query[n,b,k]. 3 launches
//                (Q scaled 0.25, K, wvT with transposed writeback rs=1/cs=512)
//  3) attn_force: per-(b,head,i-tile16) fused scores+softmax+force, atomicAdd.

// ---------------------------------------------------------------- wvf_prep
__global__ __launch_bounds__(256) void wvf_prep(
    const float* __restrict__ Wv, const float* __restrict__ Wf,
    const float* __restrict__ bv, float* __restrict__ Wvf,
    float* __restrict__ bvf)
{
    int idx = blockIdx.x * 256 + threadIdx.x;   // 0..65535
    int k = idx & 511, o = idx >> 9;            // o < 128
    float acc = 0.f;
    if (o < 96) {
        int h = o / 3, c = o % 3;
        #pragma unroll
        for (int d = 0; d < 16; ++d)
            acc += Wf[c * 512 + h * 16 + d] * Wv[(h * 16 + d) * 512 + k];
    }
    Wvf[o * 512 + k] = acc;
    if (k == 0) {
        float bacc = 0.f;
        if (o < 96) {
            int h = o / 3, c = o % 3;
            #pragma unroll
            for (int d = 0; d < 16; ++d)
                bacc += Wf[c * 512 + h * 16 + d] * bv[h * 16 + d];
        }
        bvf[o] = bacc;
    }
}

// ---------------------------------------------------------------- gemm_xwT
// C[b*bstride + row*rs + col*cs] = (sum_k x[b,row,k]*W[col,k] + bias[col])*scale
// BM=128 BN=64 BK=16, 256 threads, 8x4 micro-tile.
__global__ __launch_bounds__(256, 2) void gemm_xwT(
    const float* __restrict__ query, const float* __restrict__ W,
    const float* __restrict__ bias, float* __restrict__ C,
    float scale, int bstride, int rs, int cs)
{
    __shared__ float As[128][20];   // row stride 20 floats (80B, 16B aligned)
    __shared__ float Bst[16][68];   // k-major, pad 68 (272B, 16B aligned)
    const int tid = threadIdx.x;
    const int tx = tid & 15, ty = tid >> 4;
    const int b = blockIdx.z;
    const int row0 = blockIdx.y * 128;
    const int c0 = blockIdx.x * 64;

    float acc[8][4] = {};

    for (int kt = 0; kt < 512; kt += 16) {
        // stage A: 128 rows x 16 k = 512 float4, 2 per thread.
        // slot XOR-swizzle (k4 ^ (row>>3)&3): any 16B-aligned pad has 8*p%32==0,
        // so without the swizzle the 4 ty-rows of a read land in one bank.
        #pragma unroll
        for (int s = 0; s < 2; ++s) {
            int idx = s * 256 + tid;
            int r = idx >> 2, k4 = idx & 3;
            float4 a = *(const float4*)&query[((size_t)(row0 + r) * 4 + b) * 512 + kt + k4 * 4];
            int slot = k4 ^ ((r >> 3) & 3);
            *(float4*)&As[r][slot * 4] = a;
        }
        // stage B transposed: 64 cols x 16 k
        {
            int r = tid >> 2, k4 = tid & 3;
            float4 bv4 = *(const float4*)&W[(size_t)(c0 + r) * 512 + kt + k4 * 4];
            Bst[k4 * 4 + 0][r] = bv4.x;
            Bst[k4 * 4 + 1][r] = bv4.y;
            Bst[k4 * 4 + 2][r] = bv4.z;
            Bst[k4 * 4 + 3][r] = bv4.w;
        }
        __syncthreads();
        #pragma unroll
        for (int k4 = 0; k4 < 4; ++k4) {
            float4 a4[8];
            const int slot = k4 ^ (ty & 3);   // (r>>3)&3 == ty for r=8ty+i, i<8
            #pragma unroll
            for (int i = 0; i < 8; ++i)
                a4[i] = *(const float4*)&As[ty * 8 + i][slot * 4];
            #pragma unroll
            for (int kk = 0; kk < 4; ++kk) {
                float4 b4 = *(const float4*)&Bst[k4 * 4 + kk][tx * 4];
                #pragma unroll
                for (int i = 0; i < 8; ++i) {
                    float a = (kk == 0) ? a4[i].x : (kk == 1) ? a4[i].y
                             : (kk == 2) ? a4[i].z : a4[i].w;
                    acc[i][0] += a * b4.x;
                    acc[i][1] += a * b4.y;
                    acc[i][2] += a * b4.z;
                    acc[i][3] += a * b4.w;
                }
            }
        }
        __syncthreads();
    }
    #pragma unroll
    for (int i = 0; i < 8; ++i) {
        int row = row0 + ty * 8 + i;
        #pragma unroll
        for (int j = 0; j < 4; ++j) {
            int col = c0 + tx * 4 + j;
            C[(size_t)b * bstride + (size_t)row * rs + (size_t)col * cs] =
                (acc[i][j] + bias[col]) * scale;
        }
    }
}

// ---------------------------------------------------------------- attn_force
// One block = (b, head h, i-tile of 16 rows). 256 threads = 4 waves;
// wave w owns rows i0+4w..i0+4w+3; lane l owns j = m*64+l, m=0..7.
__global__ __launch_bounds__(256, 4) void attn_force(
    const float* __restrict__ Q, const float* __restrict__ K,
    const float* __restrict__ wvT, const float* __restrict__ abias,
    const float* __restrict__ delta, const float* __restrict__ bf,
    float* __restrict__ force)
{
    __shared__ float4 kbuf[4][512];   // [d4][j], slot j^d4 (kills 4-way write conflict)
    __shared__ float qs[16][16];

    const int tid = threadIdx.x;
    const int l = tid & 63, w = tid >> 6;
    // XCD swizzle: 8 XCDs, 4096 blocks -> each XCD gets 512 consecutive work ids,
    // so all 32 heads of an i-tile (sharing delta/K slices) live on one XCD's L2.
    const int bid = blockIdx.x;
    const int wid = (bid & 7) * 512 + (bid >> 3);
    const int b = wid >> 10;
    const int it = (wid >> 5) & 31;
    const int h = wid & 31;
    const int i0 = it * 16;

    // stage K head-slice: 512 x 16 f32 = 32 KB
    #pragma unroll
    for (int s = 0; s < 8; ++s) {
        int idx = s * 256 + tid;
        int j = idx >> 2, d4 = idx & 3;
        float4 kv = *(const float4*)&K[(size_t)(b * 512 + j) * 512 + h * 16 + d4 * 4];
        kbuf[d4][j ^ d4] = kv;
    }
    if (tid < 64) {
        int r = tid >> 2, d4 = tid & 3;
        *(float4*)&qs[r][d4 * 4] =
            *(const float4*)&Q[(size_t)(b * 512 + i0 + r) * 512 + h * 16 + d4 * 4];
    }
    __syncthreads();

    // scores init with attn_bias (the dominant, once-streamed HBM term)
    float sc[8][4];
    const size_t bbase = (size_t)(b * 32 + h) * 512 * 512;
    #pragma unroll
    for (int m = 0; m < 8; ++m)
        #pragma unroll
        for (int rr = 0; rr < 4; ++rr)
            sc[m][rr] = abias[bbase + (size_t)(i0 + w * 4 + rr) * 512 + m * 64 + l];

    // QK^T: d4 outer so only 16 q-regs live; LDS b128 feeds 16 FMAs (VALU-bound)
    #pragma unroll
    for (int d4 = 0; d4 < 4; ++d4) {
        float4 q4[4];
        #pragma unroll
        for (int rr = 0; rr < 4; ++rr)
            q4[rr] = *(const float4*)&qs[w * 4 + rr][d4 * 4];   // wave-broadcast
        #pragma unroll
        for (int m = 0; m < 8; ++m) {
            int j = m * 64 + l;
            float4 kv = kbuf[d4][j ^ d4];
            #pragma unroll
            for (int rr = 0; rr < 4; ++rr)
                sc[m][rr] += q4[rr].x * kv.x + q4[rr].y * kv.y +
                             q4[rr].z * kv.z + q4[rr].w * kv.w;
        }
    }

    // row softmax, fully in registers, width-64 shuffle reductions
    #pragma unroll
    for (int rr = 0; rr < 4; ++rr) {
        float mx = sc[0][rr];
        #pragma unroll
        for (int m = 1; m < 8; ++m) mx = fmaxf(mx, sc[m][rr]);
        #pragma unroll
        for (int off = 32; off >= 1; off >>= 1)
            mx = fmaxf(mx, __shfl_xor(mx, off));
        float sum = 0.f;
        #pragma unroll
        for (int m = 0; m < 8; ++m) {
            float p = __expf(sc[m][rr] - mx);
            sc[m][rr] = p;
            sum += p;
        }
        #pragma unroll
        for (int off = 32; off >= 1; off >>= 1)
            sum += __shfl_xor(sum, off);
        float inv = 1.0f / sum;
        #pragma unroll
        for (int m = 0; m < 8; ++m) sc[m][rr] *= inv;
    }

    // force partials: f[r][c] += p * wv[h,j,c] * delta[i,j,c]
    float f[4][3] = {};
    const float* wvb = &wvT[(size_t)(b * 128 + h * 3) * 512];
    #pragma unroll
    for (int m = 0; m < 8; ++m) {
        int j = m * 64 + l;
        float w0 = wvb[j], w1 = wvb[512 + j], w2 = wvb[1024 + j];
        #pragma unroll
        for (int rr = 0; rr < 4; ++rr) {
            const float* dp = &delta[((size_t)(b * 512 + i0 + w * 4 + rr) * 512 + j) * 3];
            float p = sc[m][rr];
            f[rr][0] += p * w0 * dp[0];
            f[rr][1] += p * w1 * dp[1];
            f[rr][2] += p * w2 * dp[2];
        }
    }

    // wave-reduce the 12 partials, one atomicAdd per (row,c) from lane 0
    #pragma unroll
    for (int rr = 0; rr < 4; ++rr)
        #pragma unroll
        for (int c = 0; c < 3; ++c) {
            float v = f[rr][c];
            #pragma unroll
            for (int off = 32; off >= 1; off >>= 1)
                v += __shfl_xor(v, off);
            f[rr][c] = v;
        }
    if (l == 0) {
        #pragma unroll
        for (int rr = 0; rr < 4; ++rr) {
            int row = i0 + w * 4 + rr;
            #pragma unroll
            for (int c = 0; c < 3; ++c) {
                float v = f[rr][c];
                if (h == 0) v += bf[c];   // exactly one head adds the output bias
                atomicAdd(&force[(size_t)(b * 512 + row) * 3 + c], v);
            }
        }
    }
}

// ---------------------------------------------------------------- launch
extern "C" void kernel_launch(void* const* d_in, const int* in_sizes, int n_in,
                              void* d_out, int out_size, void* d_ws, size_t ws_size,
                              hipStream_t stream)
{
    const float* query = (const float*)d_in[0];   // [512][4][512]
    const float* abias = (const float*)d_in[1];   // [4][32][512][512]
    const float* delta = (const float*)d_in[2];   // [4][512][512][3]
    const float* Wq    = (const float*)d_in[3];
    const float* bq    = (const float*)d_in[4];
    const float* Wk    = (const float*)d_in[5];
    const float* bk    = (const float*)d_in[6];
    const float* Wv    = (const float*)d_in[7];
    const float* bv    = (const float*)d_in[8];
    const float* Wf    = (const float*)d_in[9];   // [3][512]
    const float* bf    = (const float*)d_in[10];  // [3]

    float* ws  = (float*)d_ws;
    float* Qp  = ws;                // 4*512*512   = 1048576 f32
    float* Kp  = ws + 1048576;      // 1048576
    float* wvT = ws + 2097152;      // 4*128*512   = 262144
    float* Wvf = ws + 2359296;      // 128*512     = 65536
    float* bvf = ws + 2424832;      // 128          (total ~9.7 MB)

    hipMemsetAsync(d_out, 0, (size_t)out_size * sizeof(float), stream);

    wvf_prep<<<256, 256, 0, stream>>>(Wv, Wf, bv, Wvf, bvf);

    // Q = (x Wq^T + bq) * 0.25   -> [b][n][512]
    gemm_xwT<<<dim3(8, 4, 4), 256, 0, stream>>>(query, Wq, bq, Qp, 0.25f,
                                                512 * 512, 512, 1);
    // K = x Wk^T + bk            -> [b][n][512]
    gemm_xwT<<<dim3(8, 4, 4), 256, 0, stream>>>(query, Wk, bk, Kp, 1.0f,
                                                512 * 512, 512, 1);
    // wvT = (x Wvf^T + bvf)^T    -> [b][128][n]  (rs=1, cs=512)
    gemm_xwT<<<dim3(2, 4, 4), 256, 0, stream>>>(query, Wvf, bvf, wvT, 1.0f,
                                                128 * 512, 1, 512);

    attn_force<<<4096, 256, 0, stream>>>(Qp, Kp, wvT, abias, delta, bf,
                                         (float*)d_out);
}

// Round 7
// 337.879 us; speedup vs baseline: 1.2439x; 1.2439x over previous
//
#include <hip/hip_runtime.h>
#include <hip/hip_bf16.h>

// n=512, bsz=4, E=512, H=32 heads, d=16, scaling=0.25
//
//   force[b,i,c] = bf[c] + sum_j delta[b,i,j,c] * sum_h probs[b,h,i,j]*wv[b,h,j,c]
//   wv[b,j,h*3+c] = x[b,j,:] . Wvf[h*3+c,:] + bvf   (V GEMM folded into Wf)
//
// R4 changes (from 420us baseline: attn 130us latency-bound on ~130 scalar
// loads/thread; gemms ~280us on 128-block grids):
//  - attn_force: lane owns 8 CONSECUTIVE j -> all global loads dwordx4
//    (abias 32->8, delta 96->24, wv ->6); bias loads issued pre-sync.
//  - proj_all: single fused projection GEMM (Q|K|wvT by blockIdx.x),
//    BM=BN=64, 4x4 micro, 576 blocks = full CU coverage.

// ---------------------------------------------------------------- wvf_prep
__global__ __launch_bounds__(256) void wvf_prep(
    const float* __restrict__ Wv, const float* __restrict__ Wf,
    const float* __restrict__ bv, float* __restrict__ Wvf,
    float* __restrict__ bvf)
{
    int idx = blockIdx.x * 256 + threadIdx.x;   // 0..65535
    int k = idx & 511, o = idx >> 9;            // o < 128
    float acc = 0.f;
    if (o < 96) {
        int h = o / 3, c = o % 3;
        #pragma unroll
        for (int d = 0; d < 16; ++d)
            acc += Wf[c * 512 + h * 16 + d] * Wv[(h * 16 + d) * 512 + k];
    }
    Wvf[o * 512 + k] = acc;
    if (k == 0) {
        float bacc = 0.f;
        if (o < 96) {
            int h = o / 3, c = o % 3;
            #pragma unroll
            for (int d = 0; d < 16; ++d)
                bacc += Wf[c * 512 + h * 16 + d] * bv[h * 16 + d];
        }
        bvf[o] = bacc;
    }
}

// ---------------------------------------------------------------- proj_all
// blockIdx.x: 0..7 -> Q (scale .25), 8..15 -> K, 16..17 -> wvT (transposed
// writeback). BM=64 rows, BN=64 cols, BK=16, 256 threads, 4x4 micro-tile.
__global__ __launch_bounds__(256) void proj_all(
    const float* __restrict__ query,
    const float* __restrict__ Wq, const float* __restrict__ bq,
    const float* __restrict__ Wk, const float* __restrict__ bk,
    const float* __restrict__ Wvf, const float* __restrict__ bvf,
    float* __restrict__ Qp, float* __restrict__ Kp, float* __restrict__ wvT)
{
    __shared__ float As[64 * 16];   // [row][16k], float4 slot XOR-swizzled
    __shared__ float Bst[16][68];   // k-major, pad 68: <=2-way on read/write
    const int tid = threadIdx.x;
    const int tx = tid & 15, ty = tid >> 4;
    const int xs = blockIdx.x;
    const int sel = (xs >= 16) ? 2 : (xs >= 8 ? 1 : 0);
    const float* __restrict__ W    = sel == 0 ? Wq : sel == 1 ? Wk : Wvf;
    const float* __restrict__ bias = sel == 0 ? bq : sel == 1 ? bk : bvf;
    const float scale = sel == 0 ? 0.25f : 1.0f;
    const int c0 = (sel == 0 ? xs : sel == 1 ? xs - 8 : xs - 16) * 64;
    const int row0 = blockIdx.y * 64;
    const int b = blockIdx.z;

    const int lr = tid >> 2, lk4 = tid & 3;
    // 256 threads stage 64 rows x 16 k = 256 float4: r = tid>>2, k4 = tid&3
    float acc[4][4] = {};

    for (int kt = 0; kt < 512; kt += 16) {
        {
            int r = lr, k4 = lk4;
            float4 av = *(const float4*)&query[((size_t)(row0 + r) * 4 + b) * 512 + kt + k4 * 4];
            int slot = k4 ^ ((r >> 2) & 3);   // row-group XOR: kills 64-float alias
            *(float4*)&As[r * 16 + slot * 4] = av;
            float4 bv4 = *(const float4*)&W[(size_t)(c0 + r) * 512 + kt + k4 * 4];
            Bst[k4 * 4 + 0][r] = bv4.x;
            Bst[k4 * 4 + 1][r] = bv4.y;
            Bst[k4 * 4 + 2][r] = bv4.z;
            Bst[k4 * 4 + 3][r] = bv4.w;
        }
        __syncthreads();
        #pragma unroll
        for (int k4 = 0; k4 < 4; ++k4) {
            float4 a4[4];
            const int slot = k4 ^ (ty & 3);
            #pragma unroll
            for (int i = 0; i < 4; ++i)
                a4[i] = *(const float4*)&As[(ty * 4 + i) * 16 + slot * 4];
            #pragma unroll
            for (int kk = 0; kk < 4; ++kk) {
                float4 b4 = *(const float4*)&Bst[k4 * 4 + kk][tx * 4];
                #pragma unroll
                for (int i = 0; i < 4; ++i) {
                    float a = (kk == 0) ? a4[i].x : (kk == 1) ? a4[i].y
                             : (kk == 2) ? a4[i].z : a4[i].w;
                    acc[i][0] += a * b4.x;
                    acc[i][1] += a * b4.y;
                    acc[i][2] += a * b4.z;
                    acc[i][3] += a * b4.w;
                }
            }
        }
        __syncthreads();
    }

    if (sel < 2) {
        float* __restrict__ C = sel == 0 ? Qp : Kp;
        #pragma unroll
        for (int i = 0; i < 4; ++i) {
            int row = row0 + ty * 4 + i, col = c0 + tx * 4;
            float4 o;
            o.x = (acc[i][0] + bias[col + 0]) * scale;
            o.y = (acc[i][1] + bias[col + 1]) * scale;
            o.z = (acc[i][2] + bias[col + 2]) * scale;
            o.w = (acc[i][3] + bias[col + 3]) * scale;
            *(float4*)&C[(size_t)b * 262144 + (size_t)row * 512 + col] = o;
        }
    } else {
        // wvT[b][col][row] transposed writeback (scalar stores, tiny output)
        #pragma unroll
        for (int i = 0; i < 4; ++i) {
            int row = row0 + ty * 4 + i;
            #pragma unroll
            for (int j = 0; j < 4; ++j) {
                int col = c0 + tx * 4 + j;
                wvT[(size_t)b * 65536 + (size_t)col * 512 + row] = acc[i][j] + bias[col];
            }
        }
    }
}

// ---------------------------------------------------------------- attn_force
// One block = (b, head h, 16 i-rows). 4 waves; wave w owns rows i0+4w..+3;
// lane l owns j in [8l, 8l+8) -> every global access is a dwordx4.
__global__ __launch_bounds__(256, 4) void attn_force(
    const float* __restrict__ Q, const float* __restrict__ K,
    const float* __restrict__ wvT, const float* __restrict__ abias,
    const float* __restrict__ delta, const float* __restrict__ bf,
    float* __restrict__ force)
{
    __shared__ float4 kbuf4[4 * 512];   // [d4][sw(j)], sw = 8l + (jj^(l&7))
    __shared__ float qs[16][16];

    const int tid = threadIdx.x;
    const int l = tid & 63, w = tid >> 6;
    // XCD swizzle: all 32 heads of an i-tile stay on one XCD's L2.
    const int bid = blockIdx.x;
    const int wid = (bid & 7) * 512 + (bid >> 3);
    const int b = wid >> 10;
    const int it = (wid >> 5) & 31;
    const int h = wid & 31;
    const int i0 = it * 16;
    const int m = l & 7;

    // stage K head-slice 512x16 f32 = 32 KB, XOR-swizzled slots
    #pragma unroll
    for (int s = 0; s < 8; ++s) {
        int idx = s * 256 + tid;
        int j = idx >> 2, d4 = idx & 3;
        float4 kv = *(const float4*)&K[(size_t)(b * 512 + j) * 512 + h * 16 + d4 * 4];
        kbuf4[d4 * 512 + (j ^ ((j >> 3) & 7))] = kv;
    }
    if (tid < 64) {
        int r = tid >> 2, d4 = tid & 3;
        *(float4*)&qs[r][d4 * 4] =
            *(const float4*)&Q[(size_t)(b * 512 + i0 + r) * 512 + h * 16 + d4 * 4];
    }

    // issue attn_bias loads BEFORE the barrier (regs only; latency hides
    // under the staging drain + sync)
    const size_t bbase = (size_t)(b * 32 + h) * 262144;
    const int row_w = i0 + w * 4;
    float4 A0[4], A1[4];
    #pragma unroll
    for (int rr = 0; rr < 4; ++rr) {
        const float* ab = &abias[bbase + (size_t)(row_w + rr) * 512 + l * 8];
        A0[rr] = *(const float4*)&ab[0];
        A1[rr] = *(const float4*)&ab[4];
    }
    __syncthreads();

    float sc[4][8];
    #pragma unroll
    for (int rr = 0; rr < 4; ++rr) {
        sc[rr][0] = A0[rr].x; sc[rr][1] = A0[rr].y;
        sc[rr][2] = A0[rr].z; sc[rr][3] = A0[rr].w;
        sc[rr][4] = A1[rr].x; sc[rr][5] = A1[rr].y;
        sc[rr][6] = A1[rr].z; sc[rr][7] = A1[rr].w;
    }

    // QK^T: 4 d4 x 8 jj b128 LDS reads, 512 FMA/thread
    #pragma unroll
    for (int d4 = 0; d4 < 4; ++d4) {
        float4 q4[4];
        #pragma unroll
        for (int rr = 0; rr < 4; ++rr)
            q4[rr] = *(const float4*)&qs[w * 4 + rr][d4 * 4];   // broadcast
        #pragma unroll
        for (int jj = 0; jj < 8; ++jj) {
            float4 kv = kbuf4[d4 * 512 + 8 * l + (jj ^ m)];
            #pragma unroll
            for (int rr = 0; rr < 4; ++rr)
                sc[rr][jj] += q4[rr].x * kv.x + q4[rr].y * kv.y +
                              q4[rr].z * kv.z + q4[rr].w * kv.w;
        }
    }

    // wv loads early (consumed post-softmax)
    const float* wvb = &wvT[(size_t)(b * 128 + h * 3) * 512];
    float wvf[3][8];
    #pragma unroll
    for (int c = 0; c < 3; ++c) {
        float4 a = *(const float4*)&wvb[c * 512 + l * 8];
        float4 bq4 = *(const float4*)&wvb[c * 512 + l * 8 + 4];
        wvf[c][0] = a.x;  wvf[c][1] = a.y;  wvf[c][2] = a.z;  wvf[c][3] = a.w;
        wvf[c][4] = bq4.x; wvf[c][5] = bq4.y; wvf[c][6] = bq4.z; wvf[c][7] = bq4.w;
    }

    // row softmax, fully in registers, width-64 shuffle reductions
    #pragma unroll
    for (int rr = 0; rr < 4; ++rr) {
        float mx = sc[rr][0];
        #pragma unroll
        for (int jj = 1; jj < 8; ++jj) mx = fmaxf(mx, sc[rr][jj]);
        #pragma unroll
        for (int off = 32; off >= 1; off >>= 1)
            mx = fmaxf(mx, __shfl_xor(mx, off));
        float sum = 0.f;
        #pragma unroll
        for (int jj = 0; jj < 8; ++jj) {
            float p = __expf(sc[rr][jj] - mx);
            sc[rr][jj] = p;
            sum += p;
        }
        #pragma unroll
        for (int off = 32; off >= 1; off >>= 1)
            sum += __shfl_xor(sum, off);
        float inv = 1.0f / sum;
        #pragma unroll
        for (int jj = 0; jj < 8; ++jj) sc[rr][jj] *= inv;
    }

    // force: per row, 6 dwordx4 delta loads (24 consecutive floats/lane)
    float f[4][3] = {};
    #pragma unroll
    for (int rr = 0; rr < 4; ++rr) {
        const float* dbase = &delta[((size_t)(b * 512 + row_w + rr) * 512 + l * 8) * 3];
        float dd[24];
        #pragma unroll
        for (int q6 = 0; q6 < 6; ++q6) {
            float4 dv = *(const float4*)&dbase[q6 * 4];
            dd[q6 * 4 + 0] = dv.x; dd[q6 * 4 + 1] = dv.y;
            dd[q6 * 4 + 2] = dv.z; dd[q6 * 4 + 3] = dv.w;
        }
        #pragma unroll
        for (int jj = 0; jj < 8; ++jj) {
            float p = sc[rr][jj];
            f[rr][0] += p * wvf[0][jj] * dd[3 * jj + 0];
            f[rr][1] += p * wvf[1][jj] * dd[3 * jj + 1];
            f[rr][2] += p * wvf[2][jj] * dd[3 * jj + 2];
        }
    }

    // wave-reduce 12 partials, one atomicAdd per (row,c) from lane 0
    #pragma unroll
    for (int rr = 0; rr < 4; ++rr)
        #pragma unroll
        for (int c = 0; c < 3; ++c) {
            float v = f[rr][c];
            #pragma unroll
            for (int off = 32; off >= 1; off >>= 1)
                v += __shfl_xor(v, off);
            f[rr][c] = v;
        }
    if (l == 0) {
        #pragma unroll
        for (int rr = 0; rr < 4; ++rr) {
            int row = row_w + rr;
            #pragma unroll
            for (int c = 0; c < 3; ++c) {
                float v = f[rr][c];
                if (h == 0) v += bf[c];
                atomicAdd(&force[(size_t)(b * 512 + row) * 3 + c], v);
            }
        }
    }
}

// ---------------------------------------------------------------- launch
extern "C" void kernel_launch(void* const* d_in, const int* in_sizes, int n_in,
                              void* d_out, int out_size, void* d_ws, size_t ws_size,
                              hipStream_t stream)
{
    const float* query = (const float*)d_in[0];   // [512][4][512]
    const float* abias = (const float*)d_in[1];   // [4][32][512][512]
    const float* delta = (const float*)d_in[2];   // [4][512][512][3]
    const float* Wq    = (const float*)d_in[3];
    const float* bq    = (const float*)d_in[4];
    const float* Wk    = (const float*)d_in[5];
    const float* bk    = (const float*)d_in[6];
    const float* Wv    = (const float*)d_in[7];
    const float* bv    = (const float*)d_in[8];
    const float* Wf    = (const float*)d_in[9];   // [3][512]
    const float* bf    = (const float*)d_in[10];  // [3]

    float* ws  = (float*)d_ws;
    float* Qp  = ws;                // 4*512*512 = 1048576 f32
    float* Kp  = ws + 1048576;      // 1048576
    float* wvT = ws + 2097152;      // 4*128*512 = 262144
    float* Wvf = ws + 2359296;      // 128*512   = 65536
    float* bvf = ws + 2424832;      // 128

    hipMemsetAsync(d_out, 0, (size_t)out_size * sizeof(float), stream);

    wvf_prep<<<256, 256, 0, stream>>>(Wv, Wf, bv, Wvf, bvf);

    // Q (x8 col-tiles) | K (x8) | wvT (x2): 18 x 8 x 4 = 576 blocks
    proj_all<<<dim3(18, 8, 4), 256, 0, stream>>>(query, Wq, bq, Wk, bk,
                                                 Wvf, bvf, Qp, Kp, wvT);

    attn_force<<<4096, 256, 0, stream>>>(Qp, Kp, wvT, abias, delta, bf,
                                         (float*)d_out);
}

// Round 11
// 328.501 us; speedup vs baseline: 1.2794x; 1.0285x over previous
//
#include <hip/hip_runtime.h>
#include <hip/hip_bf16.h>

// n=512, bsz=4, E=512, H=32 heads, d=16, scaling=0.25
//
//   force[b,i,c] = bf[c] + sum_j delta[b,i,j,c] * sum_h probs[b,h,i,j]*wv[b,h,j,c]
//   wv[b,j,h*3+c] = x[b,j,:] . Wvf[h*3+c,:] + bvf   (V GEMM folded into Wf)
//
// R7 post-mortem: attn 128us latency-bound (VALU 29%, HBM 8.5%, occ 35%);
// LDS 33KB caps ~2.8 blocks/CU; whole input set is L3-resident (FETCH 79MB).
// R8 changes:
//  - attn_force: K staged as packed bf16 (16KB, XOR-swizzled) -> LDS 17.7KB,
//    launch_bounds(256,5) -> ~5 blocks/CU (2x TLP). bf16-K error ~5e-5 << 1.1e-3.
//  - proj_all: double-buffered staging (loads for t+1 in flight during t's FMAs).

__device__ __forceinline__ unsigned int rne_bf16(float x) {
    unsigned int b = __float_as_uint(x);
    return (b + 0x7fffu + ((b >> 16) & 1u)) >> 16;   // round-to-nearest-even bf16
}

// ---------------------------------------------------------------- wvf_prep
__global__ __launch_bounds__(256) void wvf_prep(
    const float* __restrict__ Wv, const float* __restrict__ Wf,
    const float* __restrict__ bv, float* __restrict__ Wvf,
    float* __restrict__ bvf)
{
    int idx = blockIdx.x * 256 + threadIdx.x;   // 0..65535
    int k = idx & 511, o = idx >> 9;            // o < 128
    float acc = 0.f;
    if (o < 96) {
        int h = o / 3, c = o % 3;
        #pragma unroll
        for (int d = 0; d < 16; ++d)
            acc += Wf[c * 512 + h * 16 + d] * Wv[(h * 16 + d) * 512 + k];
    }
    Wvf[o * 512 + k] = acc;
    if (k == 0) {
        float bacc = 0.f;
        if (o < 96) {
            int h = o / 3, c = o % 3;
            #pragma unroll
            for (int d = 0; d < 16; ++d)
                bacc += Wf[c * 512 + h * 16 + d] * bv[h * 16 + d];
        }
        bvf[o] = bacc;
    }
}

// ---------------------------------------------------------------- proj_all
// blockIdx.x: 0..7 -> Q (scale .25), 8..15 -> K, 16..17 -> wvT (transposed
// writeback). BM=64, BN=64, BK=16, 256 threads, 4x4 micro, DOUBLE-BUFFERED.
__global__ __launch_bounds__(256) void proj_all(
    const float* __restrict__ query,
    const float* __restrict__ Wq, const float* __restrict__ bq,
    const float* __restrict__ Wk, const float* __restrict__ bk,
    const float* __restrict__ Wvf, const float* __restrict__ bvf,
    float* __restrict__ Qp, float* __restrict__ Kp, float* __restrict__ wvT)
{
    __shared__ float As[2][64 * 16];   // float4-slot XOR-swizzled
    __shared__ float Bst[2][16][68];   // k-major, pad 68
    const int tid = threadIdx.x;
    const int tx = tid & 15, ty = tid >> 4;
    const int xs = blockIdx.x;
    const int sel = (xs >= 16) ? 2 : (xs >= 8 ? 1 : 0);
    const float* __restrict__ W    = sel == 0 ? Wq : sel == 1 ? Wk : Wvf;
    const float* __restrict__ bias = sel == 0 ? bq : sel == 1 ? bk : bvf;
    const float scale = sel == 0 ? 0.25f : 1.0f;
    const int c0 = (sel == 0 ? xs : sel == 1 ? xs - 8 : xs - 16) * 64;
    const int row0 = blockIdx.y * 64;
    const int b = blockIdx.z;

    const int lr = tid >> 2, lk4 = tid & 3;
    const int slot = lk4 ^ ((lr >> 2) & 3);
    const size_t abase = ((size_t)(row0 + lr) * 4 + b) * 512 + lk4 * 4;
    const size_t bbase = (size_t)(c0 + lr) * 512 + lk4 * 4;

    float acc[4][4] = {};

    // prologue: stage tile 0
    {
        float4 av = *(const float4*)&query[abase];
        float4 bw = *(const float4*)&W[bbase];
        *(float4*)&As[0][lr * 16 + slot * 4] = av;
        Bst[0][lk4 * 4 + 0][lr] = bw.x;
        Bst[0][lk4 * 4 + 1][lr] = bw.y;
        Bst[0][lk4 * 4 + 2][lr] = bw.z;
        Bst[0][lk4 * 4 + 3][lr] = bw.w;
    }
    __syncthreads();

    for (int it = 0; it < 32; ++it) {
        const int cur = it & 1;
        float4 av_n, bw_n;
        if (it < 31) {                       // issue next tile's loads now;
            int kt = (it + 1) * 16;          // latency hides under the FMAs
            av_n = *(const float4*)&query[abase + kt];
            bw_n = *(const float4*)&W[bbase + kt];
        }
        #pragma unroll
        for (int k4 = 0; k4 < 4; ++k4) {
            float4 a4[4];
            const int rslot = k4 ^ (ty & 3);   // (r>>2)&3 == ty&3 for r=4ty+i
            #pragma unroll
            for (int i = 0; i < 4; ++i)
                a4[i] = *(const float4*)&As[cur][(ty * 4 + i) * 16 + rslot * 4];
            #pragma unroll
            for (int kk = 0; kk < 4; ++kk) {
                float4 b4 = *(const float4*)&Bst[cur][k4 * 4 + kk][tx * 4];
                #pragma unroll
                for (int i = 0; i < 4; ++i) {
                    float a = (kk == 0) ? a4[i].x : (kk == 1) ? a4[i].y
                             : (kk == 2) ? a4[i].z : a4[i].w;
                    acc[i][0] += a * b4.x;
                    acc[i][1] += a * b4.y;
                    acc[i][2] += a * b4.z;
                    acc[i][3] += a * b4.w;
                }
            }
        }
        __syncthreads();
        if (it < 31) {
            *(float4*)&As[cur ^ 1][lr * 16 + slot * 4] = av_n;
            Bst[cur ^ 1][lk4 * 4 + 0][lr] = bw_n.x;
            Bst[cur ^ 1][lk4 * 4 + 1][lr] = bw_n.y;
            Bst[cur ^ 1][lk4 * 4 + 2][lr] = bw_n.z;
            Bst[cur ^ 1][lk4 * 4 + 3][lr] = bw_n.w;
        }
        __syncthreads();
    }

    if (sel < 2) {
        float* __restrict__ C = sel == 0 ? Qp : Kp;
        #pragma unroll
        for (int i = 0; i < 4; ++i) {
            int row = row0 + ty * 4 + i, col = c0 + tx * 4;
            float4 o;
            o.x = (acc[i][0] + bias[col + 0]) * scale;
            o.y = (acc[i][1] + bias[col + 1]) * scale;
            o.z = (acc[i][2] + bias[col + 2]) * scale;
            o.w = (acc[i][3] + bias[col + 3]) * scale;
            *(float4*)&C[(size_t)b * 262144 + (size_t)row * 512 + col] = o;
        }
    } else {
        #pragma unroll
        for (int i = 0; i < 4; ++i) {
            int row = row0 + ty * 4 + i;
            #pragma unroll
            for (int j = 0; j < 4; ++j) {
                int col = c0 + tx * 4 + j;
                wvT[(size_t)b * 65536 + (size_t)col * 512 + row] = acc[i][j] + bias[col];
            }
        }
    }
}

// ---------------------------------------------------------------- attn_force
// One block = (b, head h, 16 i-rows). 4 waves; wave w owns rows i0+4w..+3;
// lane l owns j in [8l, 8l+8). K staged in LDS as packed bf16 (16 KB),
// XOR swizzle addr^(((j>>3)&7)<<4) -> b128 reads at 8-claims/bank minimum.
__global__ __launch_bounds__(256, 5) void attn_force(
    const float* __restrict__ Q, const float* __restrict__ K,
    const float* __restrict__ wvT, const float* __restrict__ abias,
    const float* __restrict__ delta, const float* __restrict__ bf,
    float* __restrict__ force)
{
    __shared__ unsigned int kb[4096];   // 16 KB: row j = 8 u32 (16 bf16)
    __shared__ float qs[16][16];        // 1 KB

    const int tid = threadIdx.x;
    const int l = tid & 63, w = tid >> 6;
    const int bid = blockIdx.x;
    const int wid = (bid & 7) * 512 + (bid >> 3);   // XCD swizzle
    const int b = wid >> 10;
    const int it = (wid >> 5) & 31;
    const int h = wid & 31;
    const int i0 = it * 16;

    // stage K head-slice 512x16 as bf16 pairs
    #pragma unroll
    for (int s = 0; s < 8; ++s) {
        int idx = s * 256 + tid;
        int j = idx >> 2, d4 = idx & 3;
        float4 kv = *(const float4*)&K[(size_t)(b * 512 + j) * 512 + h * 16 + d4 * 4];
        unsigned int u0 = rne_bf16(kv.x) | (rne_bf16(kv.y) << 16);
        unsigned int u1 = rne_bf16(kv.z) | (rne_bf16(kv.w) << 16);
        int byte = (j * 32 + d4 * 8) ^ (((j >> 3) & 7) << 4);
        *(uint2*)((char*)kb + byte) = make_uint2(u0, u1);
    }
    if (tid < 64) {
        int r = tid >> 2, d4 = tid & 3;
        *(float4*)&qs[r][d4 * 4] =
            *(const float4*)&Q[(size_t)(b * 512 + i0 + r) * 512 + h * 16 + d4 * 4];
    }

    // attn_bias loads pre-barrier (latency hides under staging drain)
    const size_t bbase = (size_t)(b * 32 + h) * 262144;
    const int row_w = i0 + w * 4;
    float4 A0[4], A1[4];
    #pragma unroll
    for (int rr = 0; rr < 4; ++rr) {
        const float* ab = &abias[bbase + (size_t)(row_w + rr) * 512 + l * 8];
        A0[rr] = *(const float4*)&ab[0];
        A1[rr] = *(const float4*)&ab[4];
    }
    __syncthreads();

    float sc[4][8];
    #pragma unroll
    for (int rr = 0; rr < 4; ++rr) {
        sc[rr][0] = A0[rr].x; sc[rr][1] = A0[rr].y;
        sc[rr][2] = A0[rr].z; sc[rr][3] = A0[rr].w;
        sc[rr][4] = A1[rr].x; sc[rr][5] = A1[rr].y;
        sc[rr][6] = A1[rr].z; sc[rr][7] = A1[rr].w;
    }

    // QK^T: half (d 0..7 | 8..15) outer; per (half,jj) one b128 LDS read
    const int sw = (l & 7) << 4;
    #pragma unroll
    for (int hf = 0; hf < 2; ++hf) {
        float qh[4][8];
        #pragma unroll
        for (int rr = 0; rr < 4; ++rr) {
            float4 qa = *(const float4*)&qs[w * 4 + rr][hf * 8];
            float4 qb = *(const float4*)&qs[w * 4 + rr][hf * 8 + 4];
            qh[rr][0] = qa.x; qh[rr][1] = qa.y; qh[rr][2] = qa.z; qh[rr][3] = qa.w;
            qh[rr][4] = qb.x; qh[rr][5] = qb.y; qh[rr][6] = qb.z; qh[rr][7] = qb.w;
        }
        #pragma unroll
        for (int jj = 0; jj < 8; ++jj) {
            int byte = ((8 * l + jj) * 32 + hf * 16) ^ sw;
            uint4 u = *(const uint4*)((const char*)kb + byte);
            float k0 = __uint_as_float(u.x << 16), k1 = __uint_as_float(u.x & 0xffff0000u);
            float k2 = __uint_as_float(u.y << 16), k3 = __uint_as_float(u.y & 0xffff0000u);
            float k4 = __uint_as_float(u.z << 16), k5 = __uint_as_float(u.z & 0xffff0000u);
            float k6 = __uint_as_float(u.w << 16), k7 = __uint_as_float(u.w & 0xffff0000u);
            #pragma unroll
            for (int rr = 0; rr < 4; ++rr)
                sc[rr][jj] += qh[rr][0] * k0 + qh[rr][1] * k1 + qh[rr][2] * k2 +
                              qh[rr][3] * k3 + qh[rr][4] * k4 + qh[rr][5] * k5 +
                              qh[rr][6] * k6 + qh[rr][7] * k7;
        }
    }

    // wv loads (L2/L3-hot, consumed post-softmax)
    const float* wvb = &wvT[(size_t)(b * 128 + h * 3) * 512];
    float wvf[3][8];
    #pragma unroll
    for (int c = 0; c < 3; ++c) {
        float4 a = *(const float4*)&wvb[c * 512 + l * 8];
        float4 bq4 = *(const float4*)&wvb[c * 512 + l * 8 + 4];
        wvf[c][0] = a.x;  wvf[c][1] = a.y;  wvf[c][2] = a.z;  wvf[c][3] = a.w;
        wvf[c][4] = bq4.x; wvf[c][5] = bq4.y; wvf[c][6] = bq4.z; wvf[c][7] = bq4.w;
    }

    // row softmax, in registers, width-64 shuffle reductions
    #pragma unroll
    for (int rr = 0; rr < 4; ++rr) {
        float mx = sc[rr][0];
        #pragma unroll
        for (int jj = 1; jj < 8; ++jj) mx = fmaxf(mx, sc[rr][jj]);
        #pragma unroll
        for (int off = 32; off >= 1; off >>= 1)
            mx = fmaxf(mx, __shfl_xor(mx, off));
        float sum = 0.f;
        #pragma unroll
        for (int jj = 0; jj < 8; ++jj) {
            float p = __expf(sc[rr][jj] - mx);
            sc[rr][jj] = p;
            sum += p;
        }
        #pragma unroll
        for (int off = 32; off >= 1; off >>= 1)
            sum += __shfl_xor(sum, off);
        float inv = 1.0f / sum;
        #pragma unroll
        for (int jj = 0; jj < 8; ++jj) sc[rr][jj] *= inv;
    }

    // force: per row, 6 dwordx4 delta loads (24 consecutive floats/lane)
    float f[4][3] = {};
    #pragma unroll
    for (int rr = 0; rr < 4; ++rr) {
        const float* dbase = &delta[((size_t)(b * 512 + row_w + rr) * 512 + l * 8) * 3];
        float dd[24];
        #pragma unroll
        for (int q6 = 0; q6 < 6; ++q6) {
            float4 dv = *(const float4*)&dbase[q6 * 4];
            dd[q6 * 4 + 0] = dv.x; dd[q6 * 4 + 1] = dv.y;
            dd[q6 * 4 + 2] = dv.z; dd[q6 * 4 + 3] = dv.w;
        }
        #pragma unroll
        for (int jj = 0; jj < 8; ++jj) {
            float p = sc[rr][jj];
            f[rr][0] += p * wvf[0][jj] * dd[3 * jj + 0];
            f[rr][1] += p * wvf[1][jj] * dd[3 * jj + 1];
            f[rr][2] += p * wvf[2][jj] * dd[3 * jj + 2];
        }
    }

    // wave-reduce 12 partials, one atomicAdd per (row,c) from lane 0
    #pragma unroll
    for (int rr = 0; rr < 4; ++rr)
        #pragma unroll
        for (int c = 0; c < 3; ++c) {
            float v = f[rr][c];
            #pragma unroll
            for (int off = 32; off >= 1; off >>= 1)
                v += __shfl_xor(v, off);
            f[rr][c] = v;
        }
    if (l == 0) {
        #pragma unroll
        for (int rr = 0; rr < 4; ++rr) {
            int row = row_w + rr;
            #pragma unroll
            for (int c = 0; c < 3; ++c) {
                float v = f[rr][c];
                if (h == 0) v += bf[c];
                atomicAdd(&force[(size_t)(b * 512 + row) * 3 + c], v);
            }
        }
    }
}

// ---------------------------------------------------------------- launch
extern "C" void kernel_launch(void* const* d_in, const int* in_sizes, int n_in,
                              void* d_out, int out_size, void* d_ws, size_t ws_size,
                              hipStream_t stream)
{
    const float* query = (const float*)d_in[0];   // [512][4][512]
    const float* abias = (const float*)d_in[1];   // [4][32][512][512]
    const float* delta = (const float*)d_in[2];   // [4][512][512][3]
    const float* Wq    = (const float*)d_in[3];
    const float* bq    = (const float*)d_in[4];
    const float* Wk    = (const float*)d_in[5];
    const float* bk    = (const float*)d_in[6];
    const float* Wv    = (const float*)d_in[7];
    const float* bv    = (const float*)d_in[8];
    const float* Wf    = (const float*)d_in[9];   // [3][512]
    const float* bf    = (const float*)d_in[10];  // [3]

    float* ws  = (float*)d_ws;
    float* Qp  = ws;                // 4*512*512 = 1048576 f32
    float* Kp  = ws + 1048576;      // 1048576
    float* wvT = ws + 2097152;      // 4*128*512 = 262144
    float* Wvf = ws + 2359296;      // 128*512   = 65536
    float* bvf = ws + 2424832;      // 128

    hipMemsetAsync(d_out, 0, (size_t)out_size * sizeof(float), stream);

    wvf_prep<<<256, 256, 0, stream>>>(Wv, Wf, bv, Wvf, bvf);

    // Q (x8 col-tiles) | K (x8) | wvT (x2): 18 x 8 x 4 = 576 blocks
    proj_all<<<dim3(18, 8, 4), 256, 0, stream>>>(query, Wq, bq, Wk, bk,
                                                 Wvf, bvf, Qp, Kp, wvT);

    attn_force<<<4096, 256, 0, stream>>>(Qp, Kp, wvT, abias, delta, bf,
                                         (float*)d_out);
}